// Round 3
// baseline (979.734 us; speedup 1.0000x reference)
//
#include <hip/hip_runtime.h>
#include <hip/hip_bf16.h>
#include <hip/hip_cooperative_groups.h>

namespace cg = cooperative_groups;

typedef short bf16x4 __attribute__((ext_vector_type(4)));
typedef short bf16x8 __attribute__((ext_vector_type(8)));
typedef float f32x4  __attribute__((ext_vector_type(4)));

__device__ inline unsigned short f2us(float f) {
    __hip_bfloat16 h = __float2bfloat16(f);
    return *(unsigned short*)&h;
}
__device__ inline float us2f(unsigned short u) {
    union { unsigned int i; float f; } c; c.i = ((unsigned int)u) << 16; return c.f;
}
__device__ inline float tanh_fast(float x) {
    float xs = fminf(fmaxf(x, -20.f), 20.f);
    float t = __expf(2.f * xs);
    return 1.f - 2.f / (t + 1.f);
}

// async global->LDS, 16 B per lane; LDS dest = wave-uniform base + lane*16
__device__ inline void gload_lds16(const void* g, void* l) {
    __builtin_amdgcn_global_load_lds(
        (const __attribute__((address_space(1))) void*)g,
        (__attribute__((address_space(3))) void*)l,
        16, 0, 0);
}

struct MegaArgs {
    const float *x, *w0, *b0, *g0, *be0, *m0, *v0;
    const float *wm, *bm, *gm, *bem, *mm, *vm;
    const float *wl, *bl, *gl, *bel, *ml, *vl, *bas;
    unsigned short *Wfb, *xcl, *bufA, *bufB;
    float *Af, *Bf, *out;
    unsigned int *zp;
};

// LDS layout (152064 B): conv: [0,78336) input tile (612 px * 128 B, XOR-swizzled
// chunks: physical slot s of px p holds logical chunk s^(p&7)); [78336,152064) W.
// prep reuses [0,17408) as ushort; dyn reuses [0,84480) as f32 tile.
#define LDS_W_OFF 78336

__global__ __launch_bounds__(512, 2) void mega(MegaArgs g)
{
    __shared__ __align__(16) unsigned char smem[152064];
    const int bid = blockIdx.x;
    const int t = threadIdx.x;
    const int ln = t & 63, wv = t >> 6;
    cg::grid_group grid = cg::this_grid();

    // ================= stage P: preps =================
    {
        unsigned short* t2 = (unsigned short*)smem;   // 128*68 ushort
        for (int k = 0; k < 4; ++k) {
            int tid = bid * 4 + k;                    // 1024 (n,h) row tiles
            int pn = tid >> 7, ph = tid & 127;
            const float* xp = g.x + (size_t)pn * 64 * 16384 + ph * 128;
            if (k) __syncthreads();
            for (int i = t; i < 8192; i += 512) {
                int ci = i >> 7, w = i & 127;
                t2[w * 68 + ci] = f2us(xp[(size_t)ci * 16384 + w]);
            }
            __syncthreads();
            unsigned short* op = g.xcl + ((size_t)(pn * 16384 + ph * 128)) * 64;
            for (int i = t; i < 1024; i += 512) {
                int w = i >> 3, c8 = i & 7;
                union { bf16x4 v[2]; uint4 q; } u;
                u.v[0] = *(bf16x4*)&t2[w * 68 + c8 * 8];
                u.v[1] = *(bf16x4*)&t2[w * 68 + c8 * 8 + 4];
                *(uint4*)(op + w * 64 + c8 * 8) = u.q;
            }
        }
        // weights -> B-fragment order (co permuted: real co = (lane&15)*4 + nb)
        for (int j = t; j < 1008; j += 512) {
            int idx = bid * 1008 + j;                 // 258048 total
            int l = idx / 36864, r = idx - l * 36864;
            int tp = r >> 12, r2 = r & 4095;
            int hh = r2 >> 11, nb = (r2 >> 9) & 3, lw = (r2 >> 3) & 63, jc = r2 & 7;
            int ci = hh * 32 + (lw >> 4) * 8 + jc;
            int co = (lw & 15) * 4 + nb;
            float val = 0.f;
            if (l < 6) {
                const float* s0 = (l == 0) ? g.w0 : (g.wm + (size_t)(l - 1) * 36864);
                val = s0[(co * 64 + ci) * 9 + tp];
            } else if (co < 36) {
                val = g.wl[(co * 64 + ci) * 9 + tp];
            }
            g.Wfb[idx] = f2us(val);
        }
        // BN fold + zero page
        if (bid == 0 && t < 448) {
            int l = t >> 6, c = t & 63;
            float b, ga, be, m, v;
            bool zero = false;
            if (l == 0) {
                b = g.b0[c]; ga = g.g0[c]; be = g.be0[c]; m = g.m0[c]; v = g.v0[c];
            } else if (l < 6) {
                int o = (l - 1) * 64 + c;
                b = g.bm[o]; ga = g.gm[o]; be = g.bem[o]; m = g.mm[o]; v = g.vm[o];
            } else if (c < 36) {
                b = g.bl[c]; ga = g.gl[c]; be = g.bel[c]; m = g.ml[c]; v = g.vl[c];
            } else zero = true;
            if (zero) { g.Af[t] = 0.f; g.Bf[t] = 0.f; }
            else {
                float s = ga / sqrtf(v + 1e-5f);
                g.Af[t] = s;
                g.Bf[t] = (b - m) * s + be;
            }
        }
        if (bid == 1 && t < 64) g.zp[t] = 0u;
    }
    grid.sync();

    // ================= stage C: 7 conv layers =================
    const int bx = bid & 3, by = (bid >> 2) & 7, cn = bid >> 5;
    const int h0 = by * 16, w0c = bx * 32;
    const size_t ibase = (size_t)cn * 16384 * 64;
    const int xln = ln & 15, qd = ln >> 4;
    const int rbase = wv * 2;
    uint4 wpre[9];

    // layer-0 staging: full tile (77 insts) + W0 (72 insts) via DMA
    {
        const unsigned short* srcn = g.xcl + ibase;
        for (int i = wv; i < 77; i += 8) {
            int gg = i * 64 + ln;
            int p = gg >> 3, jj = gg & 7;
            int ty = (p * 1928) >> 16;          // p/34, exact for p<612
            int tx = p - ty * 34;
            int gy = h0 + ty - 1, gx = w0c + tx - 1;
            int js = jj ^ (p & 7);
            const unsigned short* gsrc =
                (((unsigned)gy < 128u) & ((unsigned)gx < 128u))
                    ? srcn + (ptrdiff_t)(gy * 128 + gx) * 64 + js * 8
                    : (const unsigned short*)g.zp;
            if (gg < 4896) gload_lds16(gsrc, smem + (size_t)i * 1024);
        }
        for (int i = wv; i < 72; i += 8)
            gload_lds16(g.Wfb + ((size_t)(i * 64 + ln)) * 8,
                        smem + LDS_W_OFF + (size_t)i * 1024);
        __syncthreads();
    }

#pragma unroll 1
    for (int l = 0; l < 7; ++l) {
        unsigned short* dstp = (l & 1) ? g.bufB : g.bufA;

        f32x4 acc[2][2][4];
#pragma unroll
        for (int rh = 0; rh < 2; ++rh)
#pragma unroll
            for (int hf = 0; hf < 2; ++hf)
#pragma unroll
                for (int nb = 0; nb < 4; ++nb)
                    acc[rh][hf][nb] = (f32x4){0.f, 0.f, 0.f, 0.f};

#pragma unroll
        for (int tp = 0; tp < 9; ++tp) {
            const int ky = tp / 3, kx = tp % 3;
            bf16x8 b[2][4];
#pragma unroll
            for (int hh = 0; hh < 2; ++hh)
#pragma unroll
                for (int nb = 0; nb < 4; ++nb)
                    b[hh][nb] = *(const bf16x8*)(smem + LDS_W_OFF +
                        (((((tp * 2 + hh) * 4 + nb) * 64) + ln) << 4));
#pragma unroll
            for (int rh = 0; rh < 2; ++rh) {
#pragma unroll
                for (int hf = 0; hf < 2; ++hf) {
                    const int p = (rbase + rh + ky) * 34 + hf * 16 + xln + kx;
                    const int pb = p * 128, sw = (p & 7) << 4;
#pragma unroll
                    for (int hh = 0; hh < 2; ++hh) {
                        bf16x8 a = *(const bf16x8*)(smem + pb +
                                                    (((qd + 4 * hh) << 4) ^ sw));
#pragma unroll
                        for (int nb = 0; nb < 4; ++nb)
                            acc[rh][hf][nb] = __builtin_amdgcn_mfma_f32_16x16x32_bf16(
                                a, b[hh][nb], acc[rh][hf][nb], 0, 0, 0);
                    }
                }
            }
        }

        // prefetch next layer's weights into regs (hidden under epilogue+sync)
        if (l < 6) {
            const uint4* wnext = (const uint4*)(g.Wfb + (size_t)(l + 1) * 36864);
#pragma unroll
            for (int k = 0; k < 9; ++k) wpre[k] = wnext[t + 512 * k];
        }

        // epilogue: BN + tanh -> bf16 channel-last (thread owns co 4*xln..+3)
        {
            const float* Ap = g.Af + l * 64;
            const float* Bp = g.Bf + l * 64;
            const float4 A4 = *(const float4*)&Ap[xln * 4];
            const float4 B4 = *(const float4*)&Bp[xln * 4];
#pragma unroll
            for (int rh = 0; rh < 2; ++rh) {
                const int gy = h0 + rbase + rh;
                unsigned short* dp = dstp + ibase + (size_t)(gy * 128) * 64 + xln * 4;
#pragma unroll
                for (int hf = 0; hf < 2; ++hf) {
#pragma unroll
                    for (int r = 0; r < 4; ++r) {
                        const int gx = w0c + hf * 16 + qd * 4 + r;
                        ushort4 o;
                        o.x = f2us(tanh_fast(fmaf(acc[rh][hf][0][r], A4.x, B4.x)));
                        o.y = f2us(tanh_fast(fmaf(acc[rh][hf][1][r], A4.y, B4.y)));
                        o.z = f2us(tanh_fast(fmaf(acc[rh][hf][2][r], A4.z, B4.z)));
                        o.w = f2us(tanh_fast(fmaf(acc[rh][hf][3][r], A4.w, B4.w)));
                        *(ushort4*)(dp + (size_t)gx * 64) = o;
                    }
                }
            }
        }
        if (l == 6) break;

        // drain stores + inv L1, wait all waves done with tile reads
        __threadfence();
        __syncthreads();

        // pre-stage INTERIOR of next tile (own data, just written) before sync
        const unsigned short* srcn = dstp + ibase;
        for (int i = wv; i < 64; i += 8) {
            int p = i * 8 + (ln >> 3), jj = ln & 7;       // p: 0..511 interior
            int ty = 1 + (p >> 5), tx = 1 + (p & 31);
            int pp = ty * 34 + tx;
            int gy = h0 + ty - 1, gx = w0c + tx - 1;      // always in-bounds
            int js = jj ^ (pp & 7);
            gload_lds16(srcn + (ptrdiff_t)(gy * 128 + gx) * 64 + js * 8,
                        smem + (size_t)((1 + (i >> 2)) * 34 + 1 + (i & 3) * 8) * 128);
        }

        grid.sync();

        // halo top/bottom rows via DMA (10 insts, tail-masked)
        for (int i = wv; i < 10; i += 8) {
            int row = (i < 5) ? 0 : 17;
            int i5 = (i < 5) ? i : i - 5;
            int pir = i5 * 8 + (ln >> 3), jj = ln & 7;
            int pp = row * 34 + pir;
            int gy = h0 + row - 1, gx = w0c + pir - 1;
            int js = jj ^ (pp & 7);
            const unsigned short* gsrc =
                (((unsigned)gy < 128u) & ((unsigned)gx < 128u))
                    ? srcn + (ptrdiff_t)(gy * 128 + gx) * 64 + js * 8
                    : (const unsigned short*)g.zp;
            if (pir < 34) gload_lds16(gsrc, smem + (size_t)(row * 34 + i5 * 8) * 128);
        }
        // side halo columns (32 isolated px) via reg path, swizzled write
        if (t < 256) {
            int k2 = t >> 3, jj = t & 7;
            int ty = 1 + (k2 >> 1), tx = (k2 & 1) * 33;
            int pp = ty * 34 + tx;
            int gy = h0 + ty - 1, gx = w0c + tx - 1;      // gy in-bounds
            uint4 v = make_uint4(0u, 0u, 0u, 0u);
            if ((unsigned)gx < 128u)
                v = *(const uint4*)(srcn + (ptrdiff_t)(gy * 128 + gx) * 64 + jj * 8);
            *(uint4*)(smem + (size_t)pp * 128 + ((size_t)(jj ^ (pp & 7)) << 4)) = v;
        }
        // write prefetched weights to LDS
        {
            uint4* wdst = (uint4*)(smem + LDS_W_OFF);
#pragma unroll
            for (int k = 0; k < 9; ++k) wdst[t + 512 * k] = wpre[k];
        }
        __syncthreads();
    }

    grid.sync();

    // ================= stage D: dynamic conv =================
    {
        float* tile = (float*)smem;           // 32 ci * 10 * 66 f32 = 84480 B
        const int dn = bid >> 5, ti = bid & 31;
        const int h0d = (ti >> 1) * 8, w0d = (ti & 1) * 64;
        const float* xp = g.x + (size_t)dn * 64 * 16384;
        const int tw = t & 63, th = t >> 6;
        const int h = h0d + th, w = w0d + tw;

        float bs[54];
#pragma unroll
        for (int i = 0; i < 54; ++i) bs[i] = g.bas[i];

        union { uint4 q[5]; unsigned short s[40]; } hv;
        const unsigned short* hp = g.bufA + (size_t)(dn * 16384 + h * 128 + w) * 64;
#pragma unroll
        for (int i = 0; i < 5; ++i) hv.q[i] = ((const uint4*)hp)[i];

        float coef[54];
#pragma unroll
        for (int i = 0; i < 54; ++i) coef[i] = 0.f;
#pragma unroll
        for (int m = 0; m < 6; ++m)
#pragma unroll
            for (int k = 0; k < 6; ++k) {
                float f = us2f(hv.s[m * 6 + k]);
#pragma unroll
                for (int lq = 0; lq < 9; ++lq)
                    coef[m * 9 + lq] = fmaf(f, bs[k * 9 + lq], coef[m * 9 + lq]);
            }

        float* op = g.out + (size_t)dn * 384 * 16384 + h * 128 + w;

        for (int half = 0; half < 2; ++half) {
            if (half) __syncthreads();
            for (int idx = t; idx < 21120; idx += 512) {
                int ci = idx / 660, r = idx - ci * 660;
                int y = r / 66, xw = r - y * 66;
                int gy = h0d + y - 1, gx = w0d + xw - 1;
                float v = 0.f;
                if ((unsigned)gy < 128u && (unsigned)gx < 128u)
                    v = xp[(size_t)(half * 32 + ci) * 16384 + gy * 128 + gx];
                tile[idx] = v;
            }
            __syncthreads();

#pragma unroll 1
            for (int c = 0; c < 32; ++c) {
                float xv[9];
#pragma unroll
                for (int ky = 0; ky < 3; ++ky)
#pragma unroll
                    for (int kx = 0; kx < 3; ++kx)
                        xv[ky * 3 + kx] = tile[c * 660 + (th + ky) * 66 + (tw + kx)];
                int cgc = half * 32 + c;
#pragma unroll
                for (int m = 0; m < 6; ++m) {
                    float s = 0.f;
#pragma unroll
                    for (int lq = 0; lq < 9; ++lq)
                        s = fmaf(coef[m * 9 + lq], xv[lq], s);
                    op[(size_t)(cgc * 6 + m) * 16384] = s;
                }
            }
        }
    }
}

// ---------------- launch -------------------------------------------------------
extern "C" void kernel_launch(void* const* d_in, const int* in_sizes, int n_in,
                              void* d_out, int out_size, void* d_ws, size_t ws_size,
                              hipStream_t stream)
{
    MegaArgs a;
    a.x   = (const float*)d_in[0];
    a.w0  = (const float*)d_in[1];
    a.b0  = (const float*)d_in[2];
    a.g0  = (const float*)d_in[3];
    a.be0 = (const float*)d_in[4];
    a.m0  = (const float*)d_in[5];
    a.v0  = (const float*)d_in[6];
    a.wm  = (const float*)d_in[7];
    a.bm  = (const float*)d_in[8];
    a.gm  = (const float*)d_in[9];
    a.bem = (const float*)d_in[10];
    a.mm  = (const float*)d_in[11];
    a.vm  = (const float*)d_in[12];
    a.wl  = (const float*)d_in[13];
    a.bl  = (const float*)d_in[14];
    a.gl  = (const float*)d_in[15];
    a.bel = (const float*)d_in[16];
    a.ml  = (const float*)d_in[17];
    a.vl  = (const float*)d_in[18];
    a.bas = (const float*)d_in[19];

    a.Wfb  = (unsigned short*)d_ws;                                 // 516096 B
    a.Af   = (float*)((char*)d_ws + 524288);                        // 448 floats
    a.Bf   = a.Af + 448;
    a.zp   = (unsigned int*)((char*)d_ws + (1 << 20));              // 256 B zeros
    a.xcl  = (unsigned short*)((char*)d_ws + (size_t)(2 << 20));
    a.bufA = (unsigned short*)((char*)d_ws + (size_t)(2 << 20) + 16777216);
    a.bufB = (unsigned short*)((char*)d_ws + (size_t)(2 << 20) + 2 * 16777216);
    a.out  = (float*)d_out;

    void* ka[] = {&a};
    hipLaunchCooperativeKernel((const void*)mega, dim3(256), dim3(512), ka, 0, stream);
}

// Round 4
// 403.984 us; speedup vs baseline: 2.4252x; 2.4252x over previous
//
#include <hip/hip_runtime.h>
#include <hip/hip_bf16.h>

typedef short bf16x4 __attribute__((ext_vector_type(4)));
typedef short bf16x8 __attribute__((ext_vector_type(8)));
typedef float f32x4  __attribute__((ext_vector_type(4)));

__device__ inline unsigned short f2us(float f) {
    __hip_bfloat16 h = __float2bfloat16(f);
    return *(unsigned short*)&h;
}
__device__ inline float us2f(unsigned short u) {
    union { unsigned int i; float f; } c; c.i = ((unsigned int)u) << 16; return c.f;
}
__device__ inline float tanh_fast(float x) {
    float xs = fminf(fmaxf(x, -20.f), 20.f);
    float t = __expf(2.f * xs);
    return 1.f - 2.f / (t + 1.f);
}

// async global->LDS, 16 B per lane; LDS dest = wave-uniform base + lane*16
__device__ inline void gload_lds16(const void* g, void* l) {
    __builtin_amdgcn_global_load_lds(
        (const __attribute__((address_space(1))) void*)g,
        (__attribute__((address_space(3))) void*)l,
        16, 0, 0);
}

// ---------------- fused prep: x->bf16 CL | weights->B-frag | BN fold | zeropage -
// blocks 0..1023: prep_x ; 1024..2031: prep_wf ; 2032..2033: prep_ab (+zeropage)
// Weight fragment: idx = ((((tp*2+hh)*4+nb)*64 + ln)*8 + j)
//   ci = hh*32 + (ln>>4)*8 + j ; real co = (ln&15)*4 + nb   [co-permuted for
//   vectorized epilogue stores; conv stack is channel-permutation covariant]
__global__ __launch_bounds__(256)
void prep_all(const float* __restrict__ x, unsigned short* __restrict__ xcl,
              const float* __restrict__ w0, const float* __restrict__ wm,
              const float* __restrict__ wl, unsigned short* __restrict__ Wf,
              const float* b0, const float* g0, const float* be0,
              const float* m0, const float* v0,
              const float* bm, const float* gm, const float* bem,
              const float* mm, const float* vm,
              const float* bl, const float* gl, const float* bel,
              const float* ml, const float* vl,
              float* __restrict__ Af, float* __restrict__ Bf,
              unsigned int* __restrict__ zp)
{
    const int bid = blockIdx.x;
    const int t = threadIdx.x;
    if (bid < 1024) {
        // ---- prep_x: fp32 NCHW -> bf16 channel-last [n][h][w][c]
        __shared__ unsigned short t2[128 * 68];
        int n = bid >> 7, h = bid & 127;
        const float* xp = x + (size_t)n * 64 * 16384 + h * 128;
        for (int i = t; i < 8192; i += 256) {
            int ci = i >> 7, w = i & 127;
            t2[w * 68 + ci] = f2us(xp[(size_t)ci * 16384 + w]);
        }
        __syncthreads();
        unsigned short* op = xcl + ((size_t)(n * 16384 + h * 128)) * 64;
        for (int i = t; i < 1024; i += 256) {
            int w = i >> 3, c8 = i & 7;
            union { bf16x4 v[2]; uint4 q; } u;
            u.v[0] = *(bf16x4*)&t2[w * 68 + c8 * 8];
            u.v[1] = *(bf16x4*)&t2[w * 68 + c8 * 8 + 4];
            *(uint4*)(op + w * 64 + c8 * 8) = u.q;
        }
    } else if (bid < 2032) {
        // ---- prep_wf
        int idx = (bid - 1024) * 256 + t;
        int l = idx / 36864, r = idx - l * 36864;
        int tp = r >> 12, r2 = r & 4095;
        int hh = r2 >> 11, nb = (r2 >> 9) & 3, ln = (r2 >> 3) & 63, j = r2 & 7;
        int ci = hh * 32 + (ln >> 4) * 8 + j;
        int co = (ln & 15) * 4 + nb;          // permuted co
        float val = 0.f;
        if (l < 6) {
            const float* src = (l == 0) ? w0 : (wm + (size_t)(l - 1) * 36864);
            val = src[(co * 64 + ci) * 9 + tp];
        } else if (co < 36) {
            val = wl[(co * 64 + ci) * 9 + tp];
        }
        Wf[idx] = f2us(val);
    } else {
        // ---- prep_ab + zero page
        int idx = (bid - 2032) * 256 + t;
        if (bid == 2033 && t >= 192) zp[t - 192] = 0u;   // 256 B zero page
        if (idx < 448) {
            int l = idx >> 6, c = idx & 63;
            float b, g, be, m, v;
            bool zero = false;
            if (l == 0) {
                b = b0[c]; g = g0[c]; be = be0[c]; m = m0[c]; v = v0[c];
            } else if (l < 6) {
                int o = (l - 1) * 64 + c;
                b = bm[o]; g = gm[o]; be = bem[o]; m = mm[o]; v = vm[o];
            } else if (c < 36) {
                b = bl[c]; g = gl[c]; be = bel[c]; m = ml[c]; v = vl[c];
            } else zero = true;
            if (zero) { Af[idx] = 0.f; Bf[idx] = 0.f; }
            else {
                float s = g / sqrtf(v + 1e-5f);
                Af[idx] = s;
                Bf[idx] = (b - m) * s + be;
            }
        }
    }
}

// ---------------- conv 3x3 + BN + tanh via MFMA implicit GEMM (layers 0..5) ----
// grid (4,8,8) = (w/32, h/16, n), block 512 = 8 waves, 1 block/CU (LDS 152064 B).
// Tile: 32w x 16h output px; halo 34w x 18h, channel-last bf16, row stride 128 B.
// LDS tile: px p = ty*34+tx at [p*128, p*128+128); chunk j stored at j ^ (p&7)
// (XOR swizzle via pre-swizzled global source; read applies same XOR).
// OOB halo lanes DMA from a 256-B zero page. Weights (73728 B) at LDS_W_OFF.
#define LDS_W_OFF 78336
__global__ __launch_bounds__(512, 2)
void conv_mfma(const unsigned short* __restrict__ src,
               const unsigned short* __restrict__ Wf,
               const float* __restrict__ A, const float* __restrict__ B,
               unsigned short* __restrict__ dst,
               const unsigned short* __restrict__ zp)
{
    __shared__ __align__(16) unsigned char smem[152064];   // 78336 tile + 73728 W
    const int n = blockIdx.z;
    const int h0 = blockIdx.y * 16, w0 = blockIdx.x * 32;
    const int t = threadIdx.x;
    const int ln = t & 63, wv = t >> 6;
    const int xln = ln & 15, qd = ln >> 4;
    const size_t ibase = (size_t)n * 16384 * 64;

    // stage input tile: 612 px * 8 chunks = 4896 chunks, 77 wave-insts
    const unsigned short* srcn = src + ibase;
    for (int i = wv; i < 77; i += 8) {
        int g = i * 64 + ln;
        int p = g >> 3, jj = g & 7;
        int ty = (p * 1928) >> 16;          // p/34, exact for p<612
        int tx = p - ty * 34;
        int gy = h0 + ty - 1, gx = w0 + tx - 1;
        int js = jj ^ (p & 7);              // inverse-swizzled source chunk
        const unsigned short* gsrc =
            (((unsigned)gy < 128u) & ((unsigned)gx < 128u))
                ? srcn + (ptrdiff_t)(gy * 128 + gx) * 64 + js * 8
                : zp;                        // zero page for halo OOB
        if (g < 4896) gload_lds16(gsrc, smem + (size_t)i * 1024);
    }
    // stage weights: 73728 B = 4608 chunks, 72 wave-insts, linear
    for (int i = wv; i < 72; i += 8) {
        const unsigned short* gsrc = Wf + ((size_t)(i * 64 + ln)) * 8;
        gload_lds16(gsrc, smem + LDS_W_OFF + (size_t)i * 1024);
    }
    __syncthreads();   // drains vmcnt(0): all DMA landed

    f32x4 acc[2][2][4];     // [rh][half][nb]
#pragma unroll
    for (int rh = 0; rh < 2; ++rh)
#pragma unroll
        for (int hf = 0; hf < 2; ++hf)
#pragma unroll
            for (int nb = 0; nb < 4; ++nb)
                acc[rh][hf][nb] = (f32x4){0.f, 0.f, 0.f, 0.f};

    const int rbase = wv * 2;
#pragma unroll
    for (int tp = 0; tp < 9; ++tp) {
        const int ky = tp / 3, kx = tp % 3;
        bf16x8 b[2][4];
#pragma unroll
        for (int hh = 0; hh < 2; ++hh)
#pragma unroll
            for (int nb = 0; nb < 4; ++nb)
                b[hh][nb] = *(const bf16x8*)(smem + LDS_W_OFF +
                    (((((tp * 2 + hh) * 4 + nb) * 64) + ln) << 4));
#pragma unroll
        for (int rh = 0; rh < 2; ++rh) {
#pragma unroll
            for (int hf = 0; hf < 2; ++hf) {
                const int p = (rbase + rh + ky) * 34 + hf * 16 + xln + kx;
                const int pb = p * 128, sw = (p & 7) << 4;
#pragma unroll
                for (int hh = 0; hh < 2; ++hh) {
                    bf16x8 a = *(const bf16x8*)(smem + pb +
                                                (((qd + 4 * hh) << 4) ^ sw));
#pragma unroll
                    for (int nb = 0; nb < 4; ++nb)
                        acc[rh][hf][nb] = __builtin_amdgcn_mfma_f32_16x16x32_bf16(
                            a, b[hh][nb], acc[rh][hf][nb], 0, 0, 0);
                }
            }
        }
    }

    // epilogue: BN + tanh -> bf16 channel-last; thread owns co = 4*xln..4*xln+3
    const float4 A4 = *(const float4*)&A[xln * 4];
    const float4 B4 = *(const float4*)&B[xln * 4];
#pragma unroll
    for (int rh = 0; rh < 2; ++rh) {
        const int gy = h0 + rbase + rh;
        unsigned short* dp = dst + ibase + (size_t)(gy * 128) * 64 + xln * 4;
#pragma unroll
        for (int hf = 0; hf < 2; ++hf) {
#pragma unroll
            for (int r = 0; r < 4; ++r) {
                const int gx = w0 + hf * 16 + qd * 4 + r;
                ushort4 o;
                o.x = f2us(tanh_fast(fmaf(acc[rh][hf][0][r], A4.x, B4.x)));
                o.y = f2us(tanh_fast(fmaf(acc[rh][hf][1][r], A4.y, B4.y)));
                o.z = f2us(tanh_fast(fmaf(acc[rh][hf][2][r], A4.z, B4.z)));
                o.w = f2us(tanh_fast(fmaf(acc[rh][hf][3][r], A4.w, B4.w)));
                *(ushort4*)(dp + (size_t)gx * 64) = o;
            }
        }
    }
}

// ---------------- fused layer-6 conv + dynamic conv ----------------------------
// Same conv as conv_mfma, but h7 (36 used co) stays in LDS (region reused from
// weights after last MFMA; [px][co] bf16, chunk j at j^(px&7)); then each thread
// runs the per-pixel dynamic conv for its own pixel. x staged per 32-ci half
// into the tile region as f32 [ci][18][34] (exactly 78336 B).
__global__ __launch_bounds__(512, 2)
void conv6_dyn(const unsigned short* __restrict__ src,
               const unsigned short* __restrict__ Wf,
               const float* __restrict__ A, const float* __restrict__ B,
               const float* __restrict__ x, const float* __restrict__ bases,
               float* __restrict__ out,
               const unsigned short* __restrict__ zp)
{
    __shared__ __align__(16) unsigned char smem[152064];
    const int n = blockIdx.z;
    const int h0 = blockIdx.y * 16, w0 = blockIdx.x * 32;
    const int t = threadIdx.x;
    const int ln = t & 63, wv = t >> 6;
    const int xln = ln & 15, qd = ln >> 4;
    const size_t ibase = (size_t)n * 16384 * 64;

    // ---- stage input tile + weights (identical to conv_mfma)
    const unsigned short* srcn = src + ibase;
    for (int i = wv; i < 77; i += 8) {
        int g = i * 64 + ln;
        int p = g >> 3, jj = g & 7;
        int ty = (p * 1928) >> 16;
        int tx = p - ty * 34;
        int gy = h0 + ty - 1, gx = w0 + tx - 1;
        int js = jj ^ (p & 7);
        const unsigned short* gsrc =
            (((unsigned)gy < 128u) & ((unsigned)gx < 128u))
                ? srcn + (ptrdiff_t)(gy * 128 + gx) * 64 + js * 8
                : zp;
        if (g < 4896) gload_lds16(gsrc, smem + (size_t)i * 1024);
    }
    for (int i = wv; i < 72; i += 8) {
        const unsigned short* gsrc = Wf + ((size_t)(i * 64 + ln)) * 8;
        gload_lds16(gsrc, smem + LDS_W_OFF + (size_t)i * 1024);
    }
    __syncthreads();

    f32x4 acc[2][2][4];
#pragma unroll
    for (int rh = 0; rh < 2; ++rh)
#pragma unroll
        for (int hf = 0; hf < 2; ++hf)
#pragma unroll
            for (int nb = 0; nb < 4; ++nb)
                acc[rh][hf][nb] = (f32x4){0.f, 0.f, 0.f, 0.f};

    const int rbase = wv * 2;
#pragma unroll
    for (int tp = 0; tp < 9; ++tp) {
        const int ky = tp / 3, kx = tp % 3;
        bf16x8 b[2][4];
#pragma unroll
        for (int hh = 0; hh < 2; ++hh)
#pragma unroll
            for (int nb = 0; nb < 4; ++nb)
                b[hh][nb] = *(const bf16x8*)(smem + LDS_W_OFF +
                    (((((tp * 2 + hh) * 4 + nb) * 64) + ln) << 4));
#pragma unroll
        for (int rh = 0; rh < 2; ++rh) {
#pragma unroll
            for (int hf = 0; hf < 2; ++hf) {
                const int p = (rbase + rh + ky) * 34 + hf * 16 + xln + kx;
                const int pb = p * 128, sw = (p & 7) << 4;
#pragma unroll
                for (int hh = 0; hh < 2; ++hh) {
                    bf16x8 a = *(const bf16x8*)(smem + pb +
                                                (((qd + 4 * hh) << 4) ^ sw));
#pragma unroll
                    for (int nb = 0; nb < 4; ++nb)
                        acc[rh][hf][nb] = __builtin_amdgcn_mfma_f32_16x16x32_bf16(
                            a, b[hh][nb], acc[rh][hf][nb], 0, 0, 0);
                }
            }
        }
    }
    __syncthreads();    // all tile/weight LDS reads done; regions reusable

    // ---- epilogue: BN + tanh -> bf16 h7 into LDS [px][co], chunk j at j^(px&7)
    {
        unsigned short* h7 = (unsigned short*)(smem + LDS_W_OFF);
        const float4 A4 = *(const float4*)&A[xln * 4];
        const float4 B4 = *(const float4*)&B[xln * 4];
        const int cchunk = xln >> 1, coff = (xln & 1) * 8;
#pragma unroll
        for (int rh = 0; rh < 2; ++rh) {
#pragma unroll
            for (int hf = 0; hf < 2; ++hf) {
#pragma unroll
                for (int r = 0; r < 4; ++r) {
                    const int pl = (rbase + rh) * 32 + hf * 16 + qd * 4 + r;
                    ushort4 o;
                    o.x = f2us(tanh_fast(fmaf(acc[rh][hf][0][r], A4.x, B4.x)));
                    o.y = f2us(tanh_fast(fmaf(acc[rh][hf][1][r], A4.y, B4.y)));
                    o.z = f2us(tanh_fast(fmaf(acc[rh][hf][2][r], A4.z, B4.z)));
                    o.w = f2us(tanh_fast(fmaf(acc[rh][hf][3][r], A4.w, B4.w)));
                    *(ushort4*)((unsigned char*)h7 + pl * 128 +
                                (((cchunk ^ (pl & 7)) << 4) | coff)) = o;
                }
            }
        }
    }
    __syncthreads();

    // ---- dynamic conv: 1 px/thread
    const int pxx = t & 31, py = t >> 5;
    const int h = h0 + py, w = w0 + pxx;

    float bs[54];
#pragma unroll
    for (int i = 0; i < 54; ++i) bs[i] = bases[i];

    // read own pixel's 36 features from swizzled LDS h7
    union { uint4 q[5]; unsigned short s[40]; } hv;
    {
        const int pl = py * 32 + pxx;
        const unsigned char* hb = smem + LDS_W_OFF + pl * 128;
#pragma unroll
        for (int j = 0; j < 5; ++j)
            hv.q[j] = *(const uint4*)(hb + ((j ^ (pl & 7)) << 4));
    }

    float coef[54];
#pragma unroll
    for (int i = 0; i < 54; ++i) coef[i] = 0.f;
#pragma unroll
    for (int m = 0; m < 6; ++m)
#pragma unroll
        for (int k = 0; k < 6; ++k) {
            float f = us2f(hv.s[m * 6 + k]);
#pragma unroll
            for (int lq = 0; lq < 9; ++lq)
                coef[m * 9 + lq] = fmaf(f, bs[k * 9 + lq], coef[m * 9 + lq]);
        }

    const float* xp = x + (size_t)n * 64 * 16384;
    float* op = out + (size_t)n * 384 * 16384 + h * 128 + w;
    float* tile = (float*)smem;     // [ci][18][34] f32 = 78336 B

    for (int half = 0; half < 2; ++half) {
        if (half) __syncthreads();
        // stage 32 ci x 18 x 34 fp32; idx = y*1088 + ci*34 + xw
        for (int idx = t; idx < 19584; idx += 512) {
            int y = ((idx >> 6) * 3856) >> 16;          // idx/1088, exact
            int rem = idx - y * 1088;
            int ci = (rem * 1928) >> 16;                // rem/34, exact
            int xw = rem - ci * 34;
            int gy = h0 + y - 1, gx = w0 + xw - 1;
            float v = 0.f;
            if ((unsigned)gy < 128u && (unsigned)gx < 128u)
                v = xp[(size_t)(half * 32 + ci) * 16384 + gy * 128 + gx];
            tile[ci * 612 + y * 34 + xw] = v;
        }
        __syncthreads();

#pragma unroll 1
        for (int c = 0; c < 32; ++c) {
            float xv[9];
#pragma unroll
            for (int ky = 0; ky < 3; ++ky)
#pragma unroll
                for (int kx = 0; kx < 3; ++kx)
                    xv[ky * 3 + kx] = tile[c * 612 + (py + ky) * 34 + (pxx + kx)];
            int cgc = half * 32 + c;
#pragma unroll
            for (int m = 0; m < 6; ++m) {
                float s = 0.f;
#pragma unroll
                for (int lq = 0; lq < 9; ++lq)
                    s = fmaf(coef[m * 9 + lq], xv[lq], s);
                op[(size_t)(cgc * 6 + m) * 16384] = s;
            }
        }
    }
}

// ---------------- launch -------------------------------------------------------
extern "C" void kernel_launch(void* const* d_in, const int* in_sizes, int n_in,
                              void* d_out, int out_size, void* d_ws, size_t ws_size,
                              hipStream_t stream)
{
    const float* x   = (const float*)d_in[0];
    const float* w0  = (const float*)d_in[1];
    const float* b0  = (const float*)d_in[2];
    const float* g0  = (const float*)d_in[3];
    const float* be0 = (const float*)d_in[4];
    const float* m0  = (const float*)d_in[5];
    const float* v0  = (const float*)d_in[6];
    const float* wm  = (const float*)d_in[7];
    const float* bm  = (const float*)d_in[8];
    const float* gm  = (const float*)d_in[9];
    const float* bem = (const float*)d_in[10];
    const float* mm  = (const float*)d_in[11];
    const float* vm  = (const float*)d_in[12];
    const float* wl  = (const float*)d_in[13];
    const float* bl  = (const float*)d_in[14];
    const float* gl  = (const float*)d_in[15];
    const float* bel = (const float*)d_in[16];
    const float* ml  = (const float*)d_in[17];
    const float* vl  = (const float*)d_in[18];
    const float* bas = (const float*)d_in[19];

    unsigned short* Wfb = (unsigned short*)d_ws;                    // 516096 B
    float* Af  = (float*)((char*)d_ws + 524288);                    // 448 floats
    float* Bf  = Af + 448;
    unsigned int* zp = (unsigned int*)((char*)d_ws + (1 << 20));    // 256 B zeros
    unsigned short* xcl  = (unsigned short*)((char*)d_ws + (size_t)(2  << 20));
    unsigned short* bufA = (unsigned short*)((char*)d_ws + (size_t)(2  << 20) + 16777216);
    unsigned short* bufB = (unsigned short*)((char*)d_ws + (size_t)(2  << 20) + 2 * 16777216);

    prep_all<<<2034, 256, 0, stream>>>(x, xcl, w0, wm, wl, Wfb,
                                       b0, g0, be0, m0, v0,
                                       bm, gm, bem, mm, vm,
                                       bl, gl, bel, ml, vl, Af, Bf, zp);

    dim3 cg(4, 8, 8);
    const unsigned short* zps = (const unsigned short*)zp;
    conv_mfma<<<cg, 512, 0, stream>>>(xcl,  Wfb + 0 * 36864, Af + 0,   Bf + 0,   bufA, zps);
    conv_mfma<<<cg, 512, 0, stream>>>(bufA, Wfb + 1 * 36864, Af + 64,  Bf + 64,  bufB, zps);
    conv_mfma<<<cg, 512, 0, stream>>>(bufB, Wfb + 2 * 36864, Af + 128, Bf + 128, bufA, zps);
    conv_mfma<<<cg, 512, 0, stream>>>(bufA, Wfb + 3 * 36864, Af + 192, Bf + 192, bufB, zps);
    conv_mfma<<<cg, 512, 0, stream>>>(bufB, Wfb + 4 * 36864, Af + 256, Bf + 256, bufA, zps);
    conv_mfma<<<cg, 512, 0, stream>>>(bufA, Wfb + 5 * 36864, Af + 320, Bf + 320, bufB, zps);
    conv6_dyn<<<cg, 512, 0, stream>>>(bufB, Wfb + 6 * 36864, Af + 384, Bf + 384,
                                      x, bas, (float*)d_out, zps);
}